// Round 9
// baseline (94.461 us; speedup 1.0000x reference)
//
#include <hip/hip_runtime.h>
#include <hip/hip_bf16.h>

#define SEQ_L 512
#define EDIM 300
#define HDIM 512
#define ODIM 5
#define BATCH 1024
#define VOCAB 100000
#define NCH 4
#define CPOS (SEQ_L / NCH)      // 128 interleaved positions per chunk
#define NEMB (BATCH * NCH)      // 4096 embed blocks
#define ROWU 40                 // uints per int4 row (160 B, exactly 2 lines)
#define ROWU4 10                // uint4 chunks per row
#define NG 6                    // token groups per wave (6*10=60 lanes)
#define QBLK 2048
#define TCOLS 10
#define TROWS 16
#define NTRN (TCOLS * TROWS)
#define RB 16                   // mlp rows per group

typedef float floatx4 __attribute__((ext_vector_type(4)));

__device__ __forceinline__ int nib(float v, float inv) {
  return (int)rintf(v * inv) & 0xF;  // in [-7,7] -> 4-bit two's complement
}

// ---------------- Kernel 0: quant(int4) + w1 transpose + out-init -----------
// int4 row layout (160 B): bytes 0..149 = 300 nibbles (byte b: elem 2b low,
// 2b+1 high), bytes 150..151 = zero, bytes 152..155 = f32 scale (absmax/7),
// bytes 156..159 = zero. Wave per table row; lane l owns elems 4l..4l+3
// (tail lanes 0..10 also elems 256+4l..259+4l).
__global__ __launch_bounds__(256) void prep_kernel(
    const float* __restrict__ w, const float* __restrict__ w1,
    const float* __restrict__ b2, unsigned* __restrict__ bq,
    float* __restrict__ w1t, float* __restrict__ out) {
  __shared__ float tile[32][33];
  const int blk = blockIdx.x;
  const int tid = threadIdx.x;

  if (blk >= QBLK) {
    const int aux = blk - QBLK;
    if (aux < NTRN) {  // transpose w1 [512,300] -> w1t [300,512]
      const int tc = aux % TCOLS, tr = aux / TCOLS;
      const int c0 = tc * 32, r0 = tr * 32;
      const int tx = tid & 31, ty = tid >> 5;
#pragma unroll
      for (int i = 0; i < 4; ++i) {
        const int r = r0 + ty + i * 8, c = c0 + tx;
        if (c < EDIM) tile[ty + i * 8][tx] = w1[r * EDIM + c];
      }
      __syncthreads();
#pragma unroll
      for (int i = 0; i < 4; ++i) {
        const int c = c0 + ty + i * 8, r = r0 + tx;
        if (c < EDIM) w1t[c * HDIM + r] = tile[tx][ty + i * 8];
      }
    } else {  // out = b2 (mlp accumulates with atomics)
      for (int i = tid; i < BATCH * ODIM; i += 256) out[i] = b2[i % ODIM];
    }
    return;
  }

  const int wave = tid >> 6;
  const int lane = tid & 63;
  const bool hasT = lane < 11;
  for (int r = blk * 4 + wave; r < VOCAB; r += QBLK * 4) {
    const float* row = w + (size_t)r * EDIM;
    const floatx4 v0 = __builtin_nontemporal_load(
        reinterpret_cast<const floatx4*>(row + 4 * lane));
    floatx4 v1 = {0.f, 0.f, 0.f, 0.f};
    if (hasT)
      v1 = __builtin_nontemporal_load(
          reinterpret_cast<const floatx4*>(row + 256 + 4 * lane));
    float am = fmaxf(fmaxf(fabsf(v0.x), fabsf(v0.y)),
                     fmaxf(fabsf(v0.z), fabsf(v0.w)));
    am = fmaxf(am, fmaxf(fmaxf(fabsf(v1.x), fabsf(v1.y)),
                         fmaxf(fabsf(v1.z), fabsf(v1.w))));
#pragma unroll
    for (int off = 32; off; off >>= 1) am = fmaxf(am, __shfl_xor(am, off));
    am = fmaxf(am, 1e-30f);
    const float inv = 7.f / am;
    unsigned* orow = bq + (size_t)r * ROWU;
    unsigned short* orow16 = (unsigned short*)orow;
    {
      const unsigned b0 = (unsigned)nib(v0.x, inv) | ((unsigned)nib(v0.y, inv) << 4);
      const unsigned b1 = (unsigned)nib(v0.z, inv) | ((unsigned)nib(v0.w, inv) << 4);
      orow16[lane] = (unsigned short)(b0 | (b1 << 8));
    }
    if (hasT) {
      const unsigned b0 = (unsigned)nib(v1.x, inv) | ((unsigned)nib(v1.y, inv) << 4);
      const unsigned b1 = (unsigned)nib(v1.z, inv) | ((unsigned)nib(v1.w, inv) << 4);
      orow16[64 + lane] = (unsigned short)(b0 | (b1 << 8));
    }
    if (lane == 11) orow16[75] = 0;                       // bytes 150..151
    if (lane == 12) orow[38] = __float_as_uint(am * (1.f / 7.f));  // scale
    if (lane == 13) orow[39] = 0;                         // bytes 156..159
  }
}

// ---------------- Kernel 1: int4 embed gather, 6 tokens per VMEM instr ------
// Interleaved chunks (balanced blocks). Lane l<60: group g=l/10 owns tokens
// m=6j+g of this wave's list; chunk c=l%10 owns 16 B (32 elems) of the row.
// One dwordx4 wave-instruction = 6 full token rows = 12 cache lines.
__global__ __launch_bounds__(256, 4) void embed_i4_kernel(
    const int* __restrict__ x, const uint4* __restrict__ bq,
    float* __restrict__ part, int* __restrict__ cnt) {
  __shared__ int stok[CPOS];
  __shared__ int s_nz;
  __shared__ float sred[4 * NG][320];  // (wave,g) partial rows, 30.7 KB

  const int blk = blockIdx.x;
  const int tid = threadIdx.x;
  const int b = blk >> 2;
  const int ch = blk & 3;

  if (tid == 0) s_nz = 0;
  __syncthreads();
  int tok = 0;
  if (tid < CPOS) {
    tok = x[b * SEQ_L + ch + NCH * tid];
    stok[tid] = tok;
  }
  const unsigned long long nzmask = __ballot(tid < CPOS && tok != 0);
  if (tid < CPOS && (tid & 63) == 0) atomicAdd(&s_nz, __popcll(nzmask));
  __syncthreads();
  const int n_c = s_nz;  // nonzero prefix length (in i) of this chunk

  const int wave = tid >> 6;
  const int lane = tid & 63;
  const bool act = lane < NG * ROWU4;   // 60 active lanes
  const int g = act ? (lane / ROWU4) : (NG - 1);
  const int c = act ? (lane - g * ROWU4) : (ROWU4 - 1);
  const int nt = (n_c > wave) ? ((n_c - wave + 3) >> 2) : 0;  // my tokens
  const int M = (nt + NG - 1) / NG;

  float acc[32];
#pragma unroll
  for (int i = 0; i < 32; ++i) acc[i] = 0.f;

  auto LD = [&](int jj) -> uint4 {
    int m = NG * jj + g;
    if (m >= nt) m = nt - 1;  // clamp (only reached when nt>=1)
    return bq[(size_t)stok[wave + 4 * m] * ROWU4 + c];
  };
  auto DEC = [&](const uint4& q, int jj) {
    const float sc = __shfl(__uint_as_float(q.z), g * ROWU4 + 9);
    const bool vld = act && (NG * jj + g < nt);
    const float se = vld ? sc : 0.f;
    const float se23 = (c == 9) ? 0.f : se;  // chunk9 words 2,3 = scale+pad
    const unsigned dw[4] = {q.x, q.y, q.z, q.w};
#pragma unroll
    for (int w = 0; w < 4; ++w) {
      const float s = (w >= 2) ? se23 : se;
#pragma unroll
      for (int k = 0; k < 8; ++k) {
        const int v4 = (int)(dw[w] << (28 - 4 * k)) >> 28;
        acc[8 * w + k] = fmaf(s, (float)v4, acc[8 * w + k]);
      }
    }
  };

  if (nt > 0) {
    int jj = 0;
    for (; jj + 4 <= M; jj += 4) {
      const uint4 q0 = LD(jj), q1 = LD(jj + 1), q2 = LD(jj + 2), q3 = LD(jj + 3);
      DEC(q0, jj);
      DEC(q1, jj + 1);
      DEC(q2, jj + 2);
      DEC(q3, jj + 3);
    }
    const int rem = M - jj;  // 0..3, wave-uniform
    if (rem > 0) {
      uint4 q0 = LD(jj), q1 = q0, q2 = q0;
      if (rem > 1) q1 = LD(jj + 1);
      if (rem > 2) q2 = LD(jj + 2);
      DEC(q0, jj);
      if (rem > 1) DEC(q1, jj + 1);
      if (rem > 2) DEC(q2, jj + 2);
    }
  }

  // lane (wave,g,c) owns elems 32c..32c+31 (elems >=300 are zero decodes)
  if (act) {
    float* d0 = &sred[wave * NG + g][32 * c];
#pragma unroll
    for (int q = 0; q < 8; ++q)
      *(floatx4*)(d0 + 4 * q) = {acc[4 * q], acc[4 * q + 1], acc[4 * q + 2],
                                 acc[4 * q + 3]};
  }
  __syncthreads();

  for (int d = tid; d < EDIM; d += 256) {
    float s = 0.f;
#pragma unroll
    for (int rr = 0; rr < 4 * NG; ++rr) s += sred[rr][d];
    part[(size_t)blk * EDIM + d] = s;
  }
  if (tid == 0) cnt[blk] = n_c;
}

// ---------------- Kernel 2: fused reduce + MLP (RB=16 x hidden-quarter) -----
// 256 blocks = 64 row-groups x 4 hidden-quarters; per block w1t slice is only
// 300x128 (154 KB) -> total w1t traffic 39 MB (was 157). k split over two
// 128-thread halves; w2 partials atomicAdd'ed into out (pre-init b2).
__global__ __launch_bounds__(256) void mlp_kernel(
    const float* __restrict__ part, const int* __restrict__ cnt,
    const float* __restrict__ w0, const float* __restrict__ w1t,
    const float* __restrict__ b1, const float* __restrict__ w2,
    float* __restrict__ out) {
  const int rg = blockIdx.x >> 2;
  const int qh = blockIdx.x & 3;
  const int b0 = rg * RB;
  __shared__ float sy[RB][304];
  __shared__ float sp[2][RB][128];
  __shared__ float sh[RB][128];
  __shared__ float slen[RB];

  const int tid = threadIdx.x;
  if (tid < RB) {
    const int* cb = cnt + (b0 + tid) * NCH;
    slen[tid] = (float)(cb[0] + cb[1] + cb[2] + cb[3]);  // len >= 1
  }
  __syncthreads();

  for (int i = tid; i < RB * EDIM; i += 256) {
    const int r = i / EDIM, d = i - r * EDIM;
    const float* pb = part + (size_t)(b0 + r) * NCH * EDIM;
    float s = (pb[d] + pb[EDIM + d]) + (pb[2 * EDIM + d] + pb[3 * EDIM + d]);
    const float len = slen[r];
    s += ((float)SEQ_L - len) * w0[d];
    sy[r][d] = s / len;
  }
  __syncthreads();

  const int u = tid & 127;
  const int kh = tid >> 7;           // k half: [kh*150, kh*150+150)
  const int j = qh * 128 + u;        // hidden unit

  float acc[RB];
#pragma unroll
  for (int r = 0; r < RB; ++r) acc[r] = 0.f;

  const float* wc = w1t + j;
  const int k0 = kh * 150;
#pragma unroll 2
  for (int k = k0; k < k0 + 150; ++k) {
    const float wv = wc[(size_t)k * HDIM];
#pragma unroll
    for (int r = 0; r < RB; ++r) acc[r] = fmaf(wv, sy[r][k], acc[r]);
  }
#pragma unroll
  for (int r = 0; r < RB; ++r) sp[kh][r][u] = acc[r];
  __syncthreads();

  if (kh == 0) {
    const float bb = b1[j];
#pragma unroll
    for (int r = 0; r < RB; ++r)
      sh[r][u] = fmaxf(sp[0][r][u] + sp[1][r][u] + bb, 0.f);
  }
  __syncthreads();

  const int wave = tid >> 6;
  const int lane = tid & 63;
#pragma unroll
  for (int ri = 0; ri < 4; ++ri) {
    const int rr = 4 * wave + ri;
#pragma unroll
    for (int o = 0; o < ODIM; ++o) {
      float p = fmaf(w2[o * HDIM + qh * 128 + lane], sh[rr][lane],
                     w2[o * HDIM + qh * 128 + 64 + lane] * sh[rr][64 + lane]);
#pragma unroll
      for (int off = 32; off > 0; off >>= 1) p += __shfl_down(p, off);
      if (lane == 0) atomicAdd(&out[(size_t)(b0 + rr) * ODIM + o], p);
    }
  }
}

extern "C" void kernel_launch(void* const* d_in, const int* in_sizes, int n_in,
                              void* d_out, int out_size, void* d_ws, size_t ws_size,
                              hipStream_t stream) {
  const int* x = (const int*)d_in[0];          // [1024, 512] int32
  const float* weight = (const float*)d_in[1]; // [100000, 300]
  const float* w1 = (const float*)d_in[2];     // [512, 300]
  const float* b1 = (const float*)d_in[3];     // [512]
  const float* w2 = (const float*)d_in[4];     // [5, 512]
  const float* b2 = (const float*)d_in[5];     // [5]
  float* out = (float*)d_out;                  // [1024, 5]

  // ws layout: bq [100000*160 B = 16 MB] | part [4096*300] f32 |
  //            w1t [300*512] f32 | cnt [4096] i32
  unsigned* bq = (unsigned*)d_ws;
  float* part = (float*)((char*)d_ws + (size_t)VOCAB * ROWU * 4);
  float* w1t = part + (size_t)BATCH * NCH * EDIM;
  int* cnt = (int*)(w1t + (size_t)EDIM * HDIM);

  prep_kernel<<<QBLK + NTRN + 1, 256, 0, stream>>>(weight, w1, b2, bq, w1t,
                                                   out);

  embed_i4_kernel<<<NEMB, 256, 0, stream>>>(x, (const uint4*)bq, part, cnt);

  mlp_kernel<<<256, 256, 0, stream>>>(part, cnt, weight, w1t, b1, w2, out);
}

// Round 10
// 75.146 us; speedup vs baseline: 1.2570x; 1.2570x over previous
//
#include <hip/hip_runtime.h>
#include <hip/hip_bf16.h>

#define SEQ_L 512
#define EDIM 300
#define HDIM 512
#define ODIM 5
#define BATCH 1024
#define VOCAB 100000
#define NCH 4
#define CPOS (SEQ_L / NCH)      // 128 interleaved positions per chunk
#define NEMB (BATCH * NCH)      // 4096 embed blocks
#define RB 16                   // mlp rows per group
#define U4PR 19                 // uint4 per int8 row: 300 int8 + 4B f32 scale = 304 B

typedef float floatx4 __attribute__((ext_vector_type(4)));

__device__ __forceinline__ unsigned pack4(floatx4 v, float inv) {
  const int a = (int)rintf(v.x * inv);
  const int b = (int)rintf(v.y * inv);
  const int c = (int)rintf(v.z * inv);
  const int d = (int)rintf(v.w * inv);
  return (unsigned)(a & 0xFF) | ((unsigned)(b & 0xFF) << 8) |
         ((unsigned)(c & 0xFF) << 16) | ((unsigned)(d & 0xFF) << 24);
}

// ---------------- Kernel 0: f32 table -> int8 table (R8 verbatim) -----------
__global__ __launch_bounds__(256) void quant_kernel(
    const float* __restrict__ w, unsigned* __restrict__ bq) {
  const int wave = threadIdx.x >> 6;
  const int lane = threadIdx.x & 63;
  const bool hasT = lane < 11;
  for (int r = blockIdx.x * 4 + wave; r < VOCAB; r += gridDim.x * 4) {
    const float* row = w + (size_t)r * EDIM;
    const floatx4 v0 = __builtin_nontemporal_load(
        reinterpret_cast<const floatx4*>(row + 4 * lane));
    floatx4 v1 = {0.f, 0.f, 0.f, 0.f};
    if (hasT)
      v1 = __builtin_nontemporal_load(
          reinterpret_cast<const floatx4*>(row + 256 + 4 * lane));
    float am = fmaxf(fmaxf(fabsf(v0.x), fabsf(v0.y)),
                     fmaxf(fabsf(v0.z), fabsf(v0.w)));
    am = fmaxf(am, fmaxf(fmaxf(fabsf(v1.x), fabsf(v1.y)),
                         fmaxf(fabsf(v1.z), fabsf(v1.w))));
#pragma unroll
    for (int off = 32; off; off >>= 1) am = fmaxf(am, __shfl_xor(am, off));
    am = fmaxf(am, 1e-30f);
    const float inv = 127.f / am;
    unsigned* orow = bq + (size_t)r * (U4PR * 4);
    orow[lane] = pack4(v0, inv);
    if (lane < 12) {
      const unsigned p1 =
          (lane < 11) ? pack4(v1, inv) : __float_as_uint(am * (1.f / 127.f));
      orow[64 + lane] = p1;
    }
  }
}

// ---------------- Kernel T: transpose w1 + out-init -------------------------
__global__ __launch_bounds__(256) void transpose_kernel(
    const float* __restrict__ in, const float* __restrict__ b2,
    float* __restrict__ out, float* __restrict__ outv) {
  __shared__ float tile[32][33];
  const int blk = blockIdx.x;
  const int tid = threadIdx.x;
  if (blk >= 160) {  // out = b2 (mlp accumulates via atomicAdd)
    for (int i = tid; i < BATCH * ODIM; i += 256) outv[i] = b2[i % ODIM];
    return;
  }
  const int c0 = (blk % 10) * 32;
  const int r0 = (blk / 10) * 32;
  const int tx = tid & 31;
  const int ty = tid >> 5;
#pragma unroll
  for (int i = 0; i < 4; ++i) {
    const int r = r0 + ty + i * 8, c = c0 + tx;
    if (c < EDIM) tile[ty + i * 8][tx] = in[r * EDIM + c];
  }
  __syncthreads();
#pragma unroll
  for (int i = 0; i < 4; ++i) {
    const int c = c0 + ty + i * 8, r = r0 + tx;
    if (c < EDIM) out[c * HDIM + r] = tile[tx][ty + i * 8];
  }
}

// ---------------- Kernel 1: int8 embed gather (R8 verbatim) -----------------
__global__ __launch_bounds__(256, 6) void embed_i8_kernel(
    const int* __restrict__ x, const uint4* __restrict__ bq,
    float* __restrict__ part, int* __restrict__ cnt) {
  __shared__ int stok[CPOS];
  __shared__ int s_nz;
  __shared__ float sred[12][304];  // (wave,g) -> one partial row

  const int blk = blockIdx.x;
  const int tid = threadIdx.x;
  const int b = blk >> 2;
  const int ch = blk & 3;

  if (tid == 0) s_nz = 0;
  __syncthreads();
  int tok = 0;
  if (tid < CPOS) {
    tok = x[b * SEQ_L + ch + NCH * tid];
    stok[tid] = tok;
  }
  const unsigned long long nzmask = __ballot(tid < CPOS && tok != 0);
  if (tid < CPOS && (tid & 63) == 0) atomicAdd(&s_nz, __popcll(nzmask));
  __syncthreads();
  const int n_c = s_nz;  // nonzero prefix length (in i) of this chunk

  const int wave = tid >> 6;
  const int lane = tid & 63;
  const int g = lane / U4PR;            // 0..3 (3 = dup/inactive)
  const int c = lane - g * U4PR;        // 0..18 for g<3
  const int g2 = (g < 3) ? g : 2;       // clamped for addressing
  const int c2 = (g < 3) ? c : 18;
  const int nt = (n_c > wave) ? ((n_c - wave + 3) >> 2) : 0;  // my tokens
  const int M = (nt + 2) / 3;           // instrs (3 tokens each)

  float acc[16];
#pragma unroll
  for (int i = 0; i < 16; ++i) acc[i] = 0.f;

  auto LD = [&](int jj) -> uint4 {
    int mc = 3 * jj + g2;
    if (mc >= nt) mc = nt - 1;  // clamp (M>=1 implies nt>=1)
    return bq[(size_t)stok[wave + 4 * mc] * U4PR + c2];
  };
  auto DEC = [&](const uint4& q, int jj) {
    const float sc = __shfl(__uint_as_float(q.w), 19 * g2 + 18);
    const bool vld = (g < 3) && (3 * jj + g < nt);
    const float se = vld ? sc : 0.f;
    const float se3 = (c2 == 18) ? 0.f : se;  // chunk18 word3 is the scale
    const unsigned dw[4] = {q.x, q.y, q.z, q.w};
#pragma unroll
    for (int r = 0; r < 4; ++r) {
      const float s = (r == 3) ? se3 : se;
#pragma unroll
      for (int bb = 0; bb < 4; ++bb) {
        const int v8 = (int)(signed char)(dw[r] >> (8 * bb));
        acc[4 * r + bb] = fmaf(s, (float)v8, acc[4 * r + bb]);
      }
    }
  };

  int jj = 0;
  for (; jj + 4 <= M; jj += 4) {
    const uint4 s0 = LD(jj), s1 = LD(jj + 1), s2 = LD(jj + 2), s3 = LD(jj + 3);
    DEC(s0, jj);
    DEC(s1, jj + 1);
    DEC(s2, jj + 2);
    DEC(s3, jj + 3);
  }
  const int rem = M - jj;  // 0..3, wave-uniform
  if (rem > 0) {
    uint4 s0 = LD(jj), s1 = s0, s2 = s0;
    if (rem > 1) s1 = LD(jj + 1);
    if (rem > 2) s2 = LD(jj + 2);
    DEC(s0, jj);
    if (rem > 1) DEC(s1, jj + 1);
    if (rem > 2) DEC(s2, jj + 2);
  }

  // lane (wave,g,c) owns elems 16c..16c+15 (c==18: 300..303 are zero pads)
  if (g < 3) {
    float* d0 = &sred[wave * 3 + g][16 * c];
    *(floatx4*)(d0 + 0) = {acc[0], acc[1], acc[2], acc[3]};
    *(floatx4*)(d0 + 4) = {acc[4], acc[5], acc[6], acc[7]};
    *(floatx4*)(d0 + 8) = {acc[8], acc[9], acc[10], acc[11]};
    *(floatx4*)(d0 + 12) = {acc[12], acc[13], acc[14], acc[15]};
  }
  __syncthreads();

  for (int d = tid; d < EDIM; d += 256) {
    float s = 0.f;
#pragma unroll
    for (int rr = 0; rr < 12; ++rr) s += sred[rr][d];
    part[(size_t)blk * EDIM + d] = s;
  }
  if (tid == 0) cnt[blk] = n_c;
}

// ---------------- Kernel 2: fused reduce + MLP (RB=16 x quarter, 512t) ------
// 256 blocks = 64 row-groups x 4 hidden-quarters. Per block w1t slice =
// 300x128 (1200 lines/CU vs R8's 4800). k split 4-way across thread groups
// (kh = tid>>7): kh<3 -> 19 float4-groups, kh==3 -> 18 (75 total = 300 k).
// w2 partials atomicAdd'ed into out (pre-init b2 in transpose_kernel).
__global__ __launch_bounds__(512) void mlp_kernel(
    const float* __restrict__ part, const int* __restrict__ cnt,
    const float* __restrict__ w0, const float* __restrict__ w1t,
    const float* __restrict__ b1, const float* __restrict__ w2,
    float* __restrict__ out) {
  const int rg = blockIdx.x >> 2;
  const int qh = blockIdx.x & 3;
  const int b0 = rg * RB;
  __shared__ float sy[RB][304];
  __shared__ float sp[4][RB][128];
  __shared__ float sh[RB][128];
  __shared__ float slen[RB];

  const int tid = threadIdx.x;
  if (tid < RB) {
    const int* cb = cnt + (b0 + tid) * NCH;
    slen[tid] = (float)(cb[0] + cb[1] + cb[2] + cb[3]);  // len >= 1
  }
  __syncthreads();

  for (int i = tid; i < RB * EDIM; i += 512) {
    const int r = i / EDIM, d = i - r * EDIM;
    const float* pb = part + (size_t)(b0 + r) * NCH * EDIM;
    float s = (pb[d] + pb[EDIM + d]) + (pb[2 * EDIM + d] + pb[3 * EDIM + d]);
    const float len = slen[r];
    s += ((float)SEQ_L - len) * w0[d];
    sy[r][d] = s / len;
  }
  __syncthreads();

  const int u = tid & 127;           // hidden unit within quarter
  const int kh = tid >> 7;           // k-split 0..3
  const int j = qh * 128 + u;

  float acc[RB];
#pragma unroll
  for (int r = 0; r < RB; ++r) acc[r] = 0.f;

  const int g0 = kh * 19;                       // first float4-group
  const int g1 = (kh == 3) ? 75 : (g0 + 19);    // 19,19,19,18
  const float* wc = w1t + j;
  for (int kg = g0; kg < g1; ++kg) {
    const int k = 4 * kg;
    const float w0v = wc[(size_t)k * HDIM];
    const float w1v = wc[(size_t)(k + 1) * HDIM];
    const float w2v = wc[(size_t)(k + 2) * HDIM];
    const float w3v = wc[(size_t)(k + 3) * HDIM];
#pragma unroll
    for (int r = 0; r < RB; ++r) {
      const floatx4 yv = *reinterpret_cast<const floatx4*>(&sy[r][k]);
      acc[r] += (w0v * yv.x + w1v * yv.y) + (w2v * yv.z + w3v * yv.w);
    }
  }
#pragma unroll
  for (int r = 0; r < RB; ++r) sp[kh][r][u] = acc[r];
  __syncthreads();

  if (kh == 0) {
    const float bb = b1[j];
#pragma unroll
    for (int r = 0; r < RB; ++r)
      sh[r][u] = fmaxf(((sp[0][r][u] + sp[1][r][u]) +
                        (sp[2][r][u] + sp[3][r][u])) + bb, 0.f);
  }
  __syncthreads();

  const int wave = tid >> 6;  // 0..7; wave handles rows 2w, 2w+1
  const int lane = tid & 63;
#pragma unroll
  for (int rp = 0; rp < 2; ++rp) {
    const int rr = 2 * wave + rp;
#pragma unroll
    for (int o = 0; o < ODIM; ++o) {
      float p = fmaf(w2[o * HDIM + qh * 128 + lane], sh[rr][lane],
                     w2[o * HDIM + qh * 128 + 64 + lane] * sh[rr][64 + lane]);
#pragma unroll
      for (int off = 32; off > 0; off >>= 1) p += __shfl_down(p, off);
      if (lane == 0) atomicAdd(&out[(size_t)(b0 + rr) * ODIM + o], p);
    }
  }
}

extern "C" void kernel_launch(void* const* d_in, const int* in_sizes, int n_in,
                              void* d_out, int out_size, void* d_ws, size_t ws_size,
                              hipStream_t stream) {
  const int* x = (const int*)d_in[0];          // [1024, 512] int32
  const float* weight = (const float*)d_in[1]; // [100000, 300]
  const float* w1 = (const float*)d_in[2];     // [512, 300]
  const float* b1 = (const float*)d_in[3];     // [512]
  const float* w2 = (const float*)d_in[4];     // [5, 512]
  const float* b2 = (const float*)d_in[5];     // [5]
  float* out = (float*)d_out;                  // [1024, 5]

  // ws layout: bq [100000*304 B = 30.4 MB] | part [4096*300] f32 |
  //            w1t [300*512] f32 | cnt [4096] i32
  unsigned* bq = (unsigned*)d_ws;
  float* part = (float*)((char*)d_ws + (size_t)VOCAB * U4PR * 16);
  float* w1t = part + (size_t)BATCH * NCH * EDIM;
  int* cnt = (int*)(w1t + (size_t)EDIM * HDIM);

  quant_kernel<<<2048, 256, 0, stream>>>(weight, bq);

  transpose_kernel<<<161, 256, 0, stream>>>(w1, b2, w1t, out);

  embed_i8_kernel<<<NEMB, 256, 0, stream>>>(x, (const uint4*)bq, part, cnt);

  mlp_kernel<<<256, 512, 0, stream>>>(part, cnt, weight, w1t, b1, w2, out);
}